// Round 1
// baseline (407.575 us; speedup 1.0000x reference)
//
#include <hip/hip_runtime.h>
#include <hip/hip_bf16.h>

#define T_ 256
#define B_ 16
#define S_ 64
#define D_ 256

typedef __attribute__((ext_vector_type(4))) int int4v;

// LDS-visibility-only barrier: waits DS ops, leaves global loads/stores/atomics
// in flight across the barrier (avoids the __syncthreads vmcnt(0) drain).
#define LDS_BARRIER() asm volatile("s_waitcnt lgkmcnt(0)\n\ts_barrier" ::: "memory")

// ---------------- W_x transpose: WxT[k][d] = W_x[d][k] ----------------
__global__ void k_transpose(const float* __restrict__ in, float* __restrict__ out) {
    __shared__ float tile[32][33];
    int tx = threadIdx.x & 31, ty = threadIdx.x >> 5;
    int bx = blockIdx.x & 7, by = blockIdx.x >> 3;
    tile[ty][tx] = in[(by * 32 + ty) * D_ + bx * 32 + tx];
    __syncthreads();
    out[(bx * 32 + ty) * D_ + by * 32 + tx] = tile[tx][ty];
}

// ---- wz[t*B+b][d] = { bias[d] + sum_k x[t,b,k]*WxT[k][d],  silu(z[t,b,d]) } ----
__global__ __launch_bounds__(256) void k_wxall(const float* __restrict__ x,
                                               const float* __restrict__ z,
                                               const float* __restrict__ WxT,
                                               const float* __restrict__ bias,
                                               float2* __restrict__ wz) {
    __shared__ float xs[16][D_];
    const int tid = threadIdx.x;
    const int row0 = blockIdx.x * 16;
    for (int r = 0; r < 16; ++r)
        xs[r][tid] = x[(size_t)(row0 + r) * D_ + tid];
    __syncthreads();
    float acc[16];
    float bv = bias[tid];
#pragma unroll
    for (int r = 0; r < 16; ++r) acc[r] = bv;
    for (int k = 0; k < D_; ++k) {
        float wv = WxT[k * D_ + tid];
#pragma unroll
        for (int r = 0; r < 16; ++r) acc[r] = __builtin_fmaf(wv, xs[r][k], acc[r]);
    }
    for (int r = 0; r < 16; ++r) {
        float zv = z[(size_t)(row0 + r) * D_ + tid];
        float sil = zv * __builtin_amdgcn_rcpf(1.0f + __expf(-zv));
        wz[(size_t)(row0 + r) * D_ + tid] = make_float2(acc[r], sil);
    }
}

// ---------------- main recurrence (i8 MFMA K=64) ----------------
// R13 EXPERIMENT: phase-overlap via 2 independent workgroups per CU.
// grid = 512 blocks x 256 threads (4 waves): block -> (b = blk>>5, slots
// s0 = (blk&31)*2, s0+1).  __launch_bounds__(256,2) => 2 wg/CU (8 waves/CU,
// 2/SIMD — same per-SIMD pipe load per chain-step as the old 8-wave config:
// 16 MFMA, 8 ds_read_b128, same VALU), but the two workgroups have
// INDEPENDENT s_barriers, so they drift out of phase and each fills the
// other's barrier/ds-latency stalls (~500 cyc of the measured 1210-cyc wall
// not attributable to any pipe).  Old topology matrix never had this cell:
// "2 problems/block" shares one barrier (no phase offset possible).
// Thread tid owns column d = tid (wave w = tid>>6, chain nt = quad); 2-slot
// M-replication (l16&1) puts slots 0/1 in D-regs 0/1 of every quad, so the
// shfl_xor(32) output combine disappears (1 atomic per thread; per-address
// fan-in 16->32, fire-and-forget).
// Pre-barrier tail unchanged: LDS byte = 127*tanh(pre) via
// 127 - 254/(exp(2*pre)+1) (x2 folded into dscale2/wx2), i8 RNE via the
// +1.5*2^23 magic-number trick; all float post-processing (h/127, C-partial,
// silu) deferred into the next step's ds_read latency shadow.
__global__ __launch_bounds__(256, 2) void k_rec(
    const float* __restrict__ Wh,      // [D][D] (n-major: Wh[n][k])
    const float2* __restrict__ wz,     // [T*B][D] {wx+bias, silu(z)}
    const float* __restrict__ h0,      // [B][S][D]
    const float* __restrict__ Cvec,    // [S]
    float* __restrict__ outputs,       // [T*B][D], pre-zeroed (atomic accum)
    float* __restrict__ h_out)         // [(T+1)*B][S][D]
{
    const int tid  = threadIdx.x;          // 0..255
    const int w    = tid >> 6;             // wave 0..3 (owns cols 64w..64w+63)
    const int lane = tid & 63;
    const int l16  = lane & 15;
    const int quad = lane >> 4;
    const int b    = blockIdx.x >> 5;
    const int s0   = (blockIdx.x & 31) * 2;
    const int d    = tid;                  // this thread's output column

    // ping-pong h buffer, i8. Row stride 288 B: row1 sits +8 banks from row0,
    // so the 8 distinct b128 A-chunks overlap at most 2-way (free, m136).
    __shared__ __align__(16) signed char hA8[2][2][288];

    // init hA8[0] from h0 and write h[0] = h0  (256 threads, 2 iters)
    for (int i = tid; i < 2 * D_; i += 256) {
        int r = i >> 8, dd = i & 255;
        float v = h0[(size_t)(b * S_ + s0 + r) * D_ + dd];
        float vc = fminf(fmaxf(v, -1.0f), 1.0f);
        hA8[0][r][dd] = (signed char)__float2int_rn(vc * 127.0f);
        h_out[(size_t)(b * S_ + s0 + r) * D_ + dd] = v;
    }

    // ---- pass 1: per-column absmax of Wh for cols n = 64w + nt*16 + l16 ----
    float cmax[4];
#pragma unroll
    for (int nt = 0; nt < 4; ++nt) {
        const float* wr = Wh + (size_t)(w * 64 + nt * 16 + l16) * D_ + quad * 16;
        float cm = 1e-20f;
#pragma unroll
        for (int kt = 0; kt < 4; ++kt) {
            const float* p = wr + kt * 64;
#pragma unroll
            for (int j = 0; j < 16; j += 4) {
                float4 v = *(const float4*)(p + j);
                cm = fmaxf(cm, fmaxf(fmaxf(fabsf(v.x), fabsf(v.y)),
                                     fmaxf(fabsf(v.z), fabsf(v.w))));
            }
        }
        cm = fmaxf(cm, __shfl_xor(cm, 16, 64));
        cm = fmaxf(cm, __shfl_xor(cm, 32, 64));
        cmax[nt] = cm;
    }

    // ---- pass 2: quantize Wh -> i8 B-fragments (64 VGPRs) ----
    // lane holds B[k = kt*64 + quad*16 + j][n = 64w + nt*16 + l16]
    int4v Bf[4][4];    // [kt][nt]
#pragma unroll
    for (int nt = 0; nt < 4; ++nt) {
        const float rs = 127.0f / cmax[nt];
        const float* wr = Wh + (size_t)(w * 64 + nt * 16 + l16) * D_ + quad * 16;
#pragma unroll
        for (int kt = 0; kt < 4; ++kt) {
            const float* p = wr + kt * 64;
            int4v frag;
#pragma unroll
            for (int r = 0; r < 4; ++r) {
                float4 v = *(const float4*)(p + r * 4);
                int q0 = __float2int_rn(v.x * rs) & 255;
                int q1 = __float2int_rn(v.y * rs) & 255;
                int q2 = __float2int_rn(v.z * rs) & 255;
                int q3 = __float2int_rn(v.w * rs) & 255;
                frag[r] = q0 | (q1 << 8) | (q2 << 16) | (q3 << 24);
            }
            Bf[kt][nt] = frag;
        }
    }
    // dequant scale for this thread's own chain (nt == quad), folded with
    // the tanh x2: pre2 = 2*(acc*dscale + wx). Constant-index selects only.
    {
    }
    const float dsLo    = (quad & 1) ? cmax[1] : cmax[0];
    const float dsHi    = (quad & 1) ? cmax[3] : cmax[2];
    const float dscale2 = ((quad & 2) ? dsHi : dsLo) * (2.0f / 16129.0f);
    // C coefficients pre-scaled by 1/127 (deferred values are 127*h)
    const float c0i = Cvec[s0]     * (1.0f / 127.0f);
    const float c1i = Cvec[s0 + 1] * (1.0f / 127.0f);

    // prologue: wz for t=0 and t=1; running pointers
    const float2* wzp = wz + (size_t)b * D_ + d;
    float2 wzr[2];
    wzr[0] = wzp[0];
    wzr[1] = wzp[(size_t)B_ * D_];
    wzp += (size_t)2 * B_ * D_;                 // points at t=2's row

    // deferred output state of step t-1: f0/f1 hold 127*tanh values
    float f0 = 0.f, f1 = 0.f, fsil = 0.f;
    float* hp = h_out + (size_t)(1 * B_ + b) * (S_ * D_) + (size_t)s0 * D_ + d;
    float* op = outputs + (size_t)b * D_ + d;

    __syncthreads();   // full barrier once (init visibility incl. global)

// PF = 1: prefetch wz for t+2 (main body); PF = 0: last two steps, no prefetch.
#define STEP(t, CUR, NXT, PF)                                                  \
    {                                                                          \
        const signed char* ap = &hA8[CUR][l16 & 1][quad * 16];                 \
        int4v Af0 = *(const int4v*)(ap);                                       \
        int4v Af1 = *(const int4v*)(ap + 64);                                  \
        int4v Af2 = *(const int4v*)(ap + 128);                                 \
        int4v Af3 = *(const int4v*)(ap + 192);                                 \
        if ((t) >= 1) { /* step t-1's output path, in the ds_read shadow */    \
            float hv0 = f0 * (1.0f / 127.0f);                                  \
            float hv1 = f1 * (1.0f / 127.0f);                                  \
            __builtin_nontemporal_store(hv0, hp);                              \
            __builtin_nontemporal_store(hv1, hp + D_);                         \
            hp += B_ * S_ * D_;                                                \
            float part = __builtin_fmaf(c0i, f0, c1i * f1);                    \
            atomicAdd(op, part * fsil);                                        \
            op += B_ * D_;                                                     \
        }                                                                      \
        float wx2 = wzr[CUR].x + wzr[CUR].x;                                   \
        fsil      = wzr[CUR].y;                                                \
        if (PF) { wzr[CUR] = *wzp; wzp += (size_t)B_ * D_; }                   \
        /* 8 independent 2-deep MFMA chains; dep pairs 8 instrs apart */       \
        int4v z4 = {0, 0, 0, 0};                                               \
        int4v a0A = z4, a0B = z4, a1A = z4, a1B = z4;                          \
        int4v a2A = z4, a2B = z4, a3A = z4, a3B = z4;                          \
        a0A = __builtin_amdgcn_mfma_i32_16x16x64_i8(Af0, Bf[0][0], a0A, 0, 0, 0); \
        a1A = __builtin_amdgcn_mfma_i32_16x16x64_i8(Af0, Bf[0][1], a1A, 0, 0, 0); \
        a2A = __builtin_amdgcn_mfma_i32_16x16x64_i8(Af0, Bf[0][2], a2A, 0, 0, 0); \
        a3A = __builtin_amdgcn_mfma_i32_16x16x64_i8(Af0, Bf[0][3], a3A, 0, 0, 0); \
        a0B = __builtin_amdgcn_mfma_i32_16x16x64_i8(Af1, Bf[1][0], a0B, 0, 0, 0); \
        a1B = __builtin_amdgcn_mfma_i32_16x16x64_i8(Af1, Bf[1][1], a1B, 0, 0, 0); \
        a2B = __builtin_amdgcn_mfma_i32_16x16x64_i8(Af1, Bf[1][2], a2B, 0, 0, 0); \
        a3B = __builtin_amdgcn_mfma_i32_16x16x64_i8(Af1, Bf[1][3], a3B, 0, 0, 0); \
        a0A = __builtin_amdgcn_mfma_i32_16x16x64_i8(Af2, Bf[2][0], a0A, 0, 0, 0); \
        a1A = __builtin_amdgcn_mfma_i32_16x16x64_i8(Af2, Bf[2][1], a1A, 0, 0, 0); \
        a2A = __builtin_amdgcn_mfma_i32_16x16x64_i8(Af2, Bf[2][2], a2A, 0, 0, 0); \
        a3A = __builtin_amdgcn_mfma_i32_16x16x64_i8(Af2, Bf[2][3], a3A, 0, 0, 0); \
        a0B = __builtin_amdgcn_mfma_i32_16x16x64_i8(Af3, Bf[3][0], a0B, 0, 0, 0); \
        a1B = __builtin_amdgcn_mfma_i32_16x16x64_i8(Af3, Bf[3][1], a1B, 0, 0, 0); \
        a2B = __builtin_amdgcn_mfma_i32_16x16x64_i8(Af3, Bf[3][2], a2B, 0, 0, 0); \
        a3B = __builtin_amdgcn_mfma_i32_16x16x64_i8(Af3, Bf[3][3], a3B, 0, 0, 0); \
        /* route own chain (nt == quad); D-regs 0/1 = slots 0/1 (l16&1 rep) */ \
        int uA0  = (quad & 1) ? a1A[0] : a0A[0];                               \
        int uA0b = (quad & 1) ? a3A[0] : a2A[0];                               \
        int uB0  = (quad & 1) ? a1B[0] : a0B[0];                               \
        int uB0b = (quad & 1) ? a3B[0] : a2B[0];                               \
        int sa = ((quad & 2) ? uA0b : uA0) + ((quad & 2) ? uB0b : uB0);        \
        int uA1  = (quad & 1) ? a1A[1] : a0A[1];                               \
        int uA1b = (quad & 1) ? a3A[1] : a2A[1];                               \
        int uB1  = (quad & 1) ? a1B[1] : a0B[1];                               \
        int uB1b = (quad & 1) ? a3B[1] : a2B[1];                               \
        int sb = ((quad & 2) ? uA1b : uA1) + ((quad & 2) ? uB1b : uB1);        \
        /* 127*tanh(pre) = 127 - 254/(exp(2*pre)+1); minimal chain to LDS */   \
        float e0 = __expf(__builtin_fmaf((float)sa, dscale2, wx2));            \
        float e1 = __expf(__builtin_fmaf((float)sb, dscale2, wx2));            \
        float g0 = __builtin_fmaf(-254.0f, __builtin_amdgcn_rcpf(e0 + 1.0f), 127.0f); \
        float g1 = __builtin_fmaf(-254.0f, __builtin_amdgcn_rcpf(e1 + 1.0f), 127.0f); \
        /* i8 RNE via magic number: low byte of bits(g + 1.5*2^23) */          \
        union { float f; int i; } m0, m1;                                      \
        m0.f = g0 + 12582912.0f;                                               \
        m1.f = g1 + 12582912.0f;                                               \
        hA8[NXT][0][d] = (signed char)m0.i;                                    \
        hA8[NXT][1][d] = (signed char)m1.i;                                    \
        f0 = g0; f1 = g1;                                                      \
        LDS_BARRIER();                                                         \
    }

    for (int t2 = 0; t2 < T_ - 2; t2 += 2) {
        STEP(t2, 0, 1, 1)
        STEP(t2 + 1, 1, 0, 1)
    }
    STEP(T_ - 2, 0, 1, 0)
    STEP(T_ - 1, 1, 0, 0)
#undef STEP

    // tail: flush step T-1's output path
    {
        float hv0 = f0 * (1.0f / 127.0f);
        float hv1 = f1 * (1.0f / 127.0f);
        __builtin_nontemporal_store(hv0, hp);
        __builtin_nontemporal_store(hv1, hp + D_);
        float part = __builtin_fmaf(c0i, f0, c1i * f1);
        atomicAdd(op, part * fsil);
    }
}

extern "C" void kernel_launch(void* const* d_in, const int* in_sizes, int n_in,
                              void* d_out, int out_size, void* d_ws, size_t ws_size,
                              hipStream_t stream) {
    const float* x    = (const float*)d_in[0];
    const float* z    = (const float*)d_in[1];
    const float* h0   = (const float*)d_in[2];
    const float* W_x  = (const float*)d_in[3];
    const float* W_h  = (const float*)d_in[4];
    const float* bias = (const float*)d_in[5];
    const float* C    = (const float*)d_in[6];

    float* outputs = (float*)d_out;                     // [T*B*D]
    float* h_out   = outputs + (size_t)T_ * B_ * D_;    // [(T+1)*B*S*D]

    float*  WxT = (float*)d_ws;                         // D*D floats
    float2* wz  = (float2*)(WxT + D_ * D_);             // T*B*D float2

    hipMemsetAsync(outputs, 0, (size_t)T_ * B_ * D_ * sizeof(float), stream);
    k_transpose<<<64, 1024, 0, stream>>>(W_x, WxT);
    k_wxall<<<T_ * B_ / 16, 256, 0, stream>>>(x, z, WxT, bias, wz);
    k_rec<<<B_ * S_ / 2, 256, 0, stream>>>(W_h, wz, h0, C, outputs, h_out);
}